// Round 20
// baseline (266.617 us; speedup 1.0000x reference)
//
#include <hip/hip_runtime.h>

#define EPSf 1e-5f
#define NPAD 72     // f2w/win ci stride: 16B-aligned b128, 2-way-free banks
#define CSTR 168    // cbuf row stride: 336B, 16B-aligned, period-8 bank spread

typedef __attribute__((ext_vector_type(8))) short short8;
typedef __attribute__((ext_vector_type(4))) float f32x4;

static __device__ __forceinline__ unsigned short f32_to_bf16(float f) {
    unsigned int u = __float_as_uint(f);
    unsigned int r = (u + 0x7FFFu + ((u >> 16) & 1u)) >> 16;
    return (unsigned short)r;
}
static __device__ __forceinline__ float bf16_to_f32(unsigned short h) {
    return __uint_as_float(((unsigned int)h) << 16);
}

// Reorder conv weights into MFMA-fragment order (r17-validated). grid 2, block 256.
__global__ __launch_bounds__(256) void prep_wfrag(
    const float* __restrict__ wK, const float* __restrict__ wQ,
    unsigned short* __restrict__ fK, unsigned short* __restrict__ fQ)
{
    const float* src = (blockIdx.x == 0) ? wK : wQ;
    unsigned short* dst = (blockIdx.x == 0) ? fK : fQ;
    const int t = threadIdx.x;
#pragma unroll
    for (int it = 0; it < 18; ++it) {
        int s = t + it * 256;                 // 0..4607
        int l = s & 63, rest = s >> 6;
        int kc = rest % 18, wv = rest / 18;
        int n = l & 15, kg = l >> 4;
        int cout = wv * 16 + n, cih = kc & 1, tap = kc >> 1;
        short8 v;
#pragma unroll
        for (int e = 0; e < 8; ++e) {
            int ci = cih * 32 + kg * 8 + e;
            ((unsigned short*)&v)[e] = f32_to_bf16(src[(size_t)cout * 576 + ci * 9 + tap]);
        }
        *(short8*)&dst[(size_t)s * 8] = v;
    }
}

// Both 3x3 convs in ONE dispatch: grid (12,24,8), z = which*4 + b.
// __launch_bounds__(256,4) caps VGPR at 128 -> 4 blocks/CU (was 3 at 136 VGPR).
// bfrag split into two 9-entry batches to fit the budget.
__global__ __launch_bounds__(256, 4) void conv3x3_mfma2(
    const float* __restrict__ fm1, const float* __restrict__ fm2,
    const unsigned short* __restrict__ wfK, const unsigned short* __restrict__ wfQ,
    const float* __restrict__ bK, const float* __restrict__ gK,
    const float* __restrict__ beK, const float* __restrict__ mK, const float* __restrict__ vK,
    const float* __restrict__ bQ, const float* __restrict__ gQ,
    const float* __restrict__ beQ, const float* __restrict__ mQ, const float* __restrict__ vQ,
    unsigned short* __restrict__ f1o, unsigned short* __restrict__ f2o)
{
    __shared__ unsigned short win[10 * 18 * NPAD];   // 25.9 KB bf16 [row][col][ci]
    const int t  = threadIdx.x;
    const int x0 = blockIdx.x << 4, y0 = blockIdx.y << 3;
    const int b  = blockIdx.z & 3, which = blockIdx.z >> 2;
    const float* in = which ? fm2 : fm1;
    const unsigned short* wfrag = which ? wfQ : wfK;
    const float* bias = which ? bQ : bK;
    const float* bn_g = which ? gQ : gK;
    const float* bn_be = which ? beQ : beK;
    const float* bn_m = which ? mQ : mK;
    const float* bn_v = which ? vQ : vK;
    unsigned short* out = which ? f2o : f1o;
    const float* inb = in + (size_t)b * 64 * 36864;

    // Edge columns never produced by the clamped reads: pre-zero (no race).
    if (x0 == 0) {
        for (int i = t; i < 640; i += 256) {
            int ci = i & 63, row = i >> 6;
            win[(row * 18 + 0) * NPAD + ci] = 0;
        }
    } else if (x0 == 176) {
        for (int i = t; i < 640; i += 256) {
            int ci = i & 63, row = i >> 6;
            win[(row * 18 + 17) * NPAD + ci] = 0;
        }
    }

    // Coalesced staging (r19): q = p*6 + j, p=(row,ci), j = 6 float4s over window.
    const int gxs = (x0 == 0) ? 0 : ((x0 == 176) ? 168 : x0 - 4);   // aligned, in-image
#pragma unroll
    for (int it = 0; it < 15; ++it) {
        int q = t + (it << 8);               // 0..3839
        int p = q / 6, j = q - p * 6;
        int ci = p & 63, row = p >> 6;
        int gy = y0 - 1 + row;
        bool rowok = (gy >= 0 && gy < 192);
        int gya = rowok ? gy : (gy < 0 ? 0 : 191);
        int gxa = gxs + j * 4;               // 16B-aligned, fully in-image
        f32x4 v = *(const f32x4*)(inb + (size_t)ci * 36864 + gya * 192 + gxa);
#pragma unroll
        for (int e = 0; e < 4; ++e) {
            int col = gxa + e - (x0 - 1);
            if (col >= 0 && col < 18)
                win[(row * 18 + col) * NPAD + ci] = f32_to_bf16(rowok ? v[e] : 0.f);
        }
    }

    const int wv = t >> 6, l = t & 63;
    const int n  = l & 15, kg = l >> 4;
    const int cout = wv * 16 + n;
    const unsigned short* wf = wfrag + (size_t)wv * 9216 + l * 8;

    const float inv = bn_g[cout] / sqrtf(bn_v[cout] + EPSf);
    const float sh  = (bias[cout] - bn_m[cout]) * inv + bn_be[cout];

    f32x4 acc[8];
#pragma unroll
    for (int mt = 0; mt < 8; ++mt) acc[mt] = (f32x4){0.f, 0.f, 0.f, 0.f};

    __syncthreads();

    // Two bfrag batches of 9 (VGPR budget): load 9 frags, run 9 K-chunks.
#pragma unroll
    for (int half = 0; half < 2; ++half) {
        short8 bfrag[9];
#pragma unroll
        for (int k9 = 0; k9 < 9; ++k9)
            bfrag[k9] = *(const short8*)&wf[(half * 9 + k9) * 512];
#pragma unroll
        for (int k9 = 0; k9 < 9; ++k9) {
            int kc = half * 9 + k9;
            int cih = kc & 1, tap = kc >> 1;
            int ky = tap / 3, kx = tap - ky * 3;
            const int cbase = cih * 32 + kg * 8;
            const int col = n + kx;
#pragma unroll
            for (int mt = 0; mt < 8; ++mt) {
                const unsigned short* ap = &win[((mt + ky) * 18 + col) * NPAD + cbase];
                short8 a = *(const short8*)ap;
                acc[mt] = __builtin_amdgcn_mfma_f32_16x16x32_bf16(a, bfrag[k9], acc[mt], 0, 0, 0);
            }
        }
    }

    const size_t pbase = (size_t)b * 36864;
#pragma unroll
    for (int mt = 0; mt < 8; ++mt) {
#pragma unroll
        for (int r = 0; r < 4; ++r) {
            int pxx = kg * 4 + r;
            float v = fmaf(acc[mt][r], inv, sh);
            out[(pbase + (size_t)(y0 + mt) * 192 + x0 + pxx) * 64 + cout] =
                f32_to_bf16(v > 0.f ? v : 0.f);
        }
    }
}

// Fused corr(R=4) + 1x1 conv, full MFMA — EXACT round-16 version (validated).
__global__ __launch_bounds__(256) void corr_conv1x1_mfma(
    const unsigned short* __restrict__ f1, const unsigned short* __restrict__ f2,
    const float* __restrict__ qw,    // [64][145]
    const float* __restrict__ qb,
    const float* __restrict__ qg, const float* __restrict__ qbe,
    const float* __restrict__ qm, const float* __restrict__ qv,
    float* __restrict__ out)         // [B,64,192,192] f32
{
    __shared__ unsigned short smem[20736 + 64 * CSTR];   // 62976 B
    unsigned short* f2w  = smem;            // [12r][24u][72c-pad]
    unsigned short* cbuf = smem + 20736;    // [64px][168]: corr[0..81) | 0 | f1[88..152) | 0

    const int t  = threadIdx.x;
    const int x0 = blockIdx.x << 4, y0 = blockIdx.y << 2;
    const int b  = blockIdx.z;
    const int wv = t >> 6, l = t & 63;
    const int n15 = l & 15, kg = l >> 4, hi4 = kg << 2;
    const size_t pbase = (size_t)b * 36864;

#pragma unroll
    for (int i = 0; i < 9; ++i) {
        int q = t + (i << 8);                 // 0..2303
        int r = q / 192, rem = q - r * 192;
        int u = rem >> 3, j = rem & 7;
        int gy = y0 - 4 + r, gx = x0 - 4 + u;
        short8 v = {0, 0, 0, 0, 0, 0, 0, 0};
        if (gy >= 0 && gy < 192 && gx >= 0 && gx < 192)
            v = *(const short8*)&f2[(pbase + (size_t)gy * 192 + gx) * 64 + j * 8];
        *(short8*)&f2w[(r * 24 + u) * NPAD + j * 8] = v;
    }
#pragma unroll
    for (int i = 0; i < 2; ++i) {
        int q = t + (i << 8);                 // 0..511
        int px = q >> 3, j = q & 7;
        int gy = y0 + (px >> 4), gx = x0 + (px & 15);
        short8 v = *(const short8*)&f1[(pbase + (size_t)gy * 192 + gx) * 64 + j * 8];
        *(short8*)&cbuf[px * CSTR + 88 + j * 8] = v;
    }
    if (t < 64) {
#pragma unroll
        for (int d = 81; d < 88; ++d)  cbuf[t * CSTR + d] = 0;
#pragma unroll
        for (int d = 152; d < 168; ++d) cbuf[t * CSTR + d] = 0;
    }

    const int cout_a = wv * 16 + n15;
    short8 w2[5];
#pragma unroll
    for (int s = 0; s < 5; ++s) {
        short8 v;
#pragma unroll
        for (int e = 0; e < 8; ++e) {
            int k = s * 32 + kg * 8 + e;
            float w = 0.f;
            if (k < 81)                  w = qw[cout_a * 145 + k];
            else if (k >= 88 && k < 152) w = qw[cout_a * 145 + k - 7];
            ((unsigned short*)&v)[e] = f32_to_bf16(w);
        }
        w2[s] = v;
    }
    float inv4[4], sh4[4];
#pragma unroll
    for (int r = 0; r < 4; ++r) {
        int c = wv * 16 + hi4 + r;
        inv4[r] = qg[c] / sqrtf(qv[c] + EPSf);
        sh4[r]  = (qb[c] - qm[c]) * inv4[r] + qbe[c];
    }

    __syncthreads();

    const int ty = wv, tx = n15;
    short8 bfr0 = *(const short8*)&cbuf[(ty * 16 + n15) * CSTR + 88 + kg * 8];
    short8 bfr1 = *(const short8*)&cbuf[(ty * 16 + n15) * CSTR + 120 + kg * 8];
    const int rowb = (ty * 16 + tx) * CSTR;
#pragma unroll
    for (int Mt = 0; Mt < 14; ++Mt) {
        int row = ty * 24 + Mt * 16 + n15;    // = (ty+bb)*24 + u
        short8 a0 = *(const short8*)&f2w[row * NPAD + kg * 8];
        short8 a1 = *(const short8*)&f2w[row * NPAD + 32 + kg * 8];
        f32x4 acc = (f32x4){0.f, 0.f, 0.f, 0.f};
        acc = __builtin_amdgcn_mfma_f32_16x16x32_bf16(a0, bfr0, acc, 0, 0, 0);
        acc = __builtin_amdgcn_mfma_f32_16x16x32_bf16(a1, bfr1, acc, 0, 0, 0);
#pragma unroll
        for (int r = 0; r < 4; ++r) {
            int m  = Mt * 16 + hi4 + r;       // D row
            int bb = m / 24;
            int u  = m - bb * 24;
            int a  = u - tx;
            if (m < 216 && a >= 0 && a <= 8)
                cbuf[rowb + a * 9 + bb] = f32_to_bf16(acc[r] * 0.125f);
        }
    }
    __syncthreads();

    f32x4 acc2[4];
#pragma unroll
    for (int Nt = 0; Nt < 4; ++Nt) {
        acc2[Nt] = (f32x4){0.f, 0.f, 0.f, 0.f};
#pragma unroll
        for (int s = 0; s < 5; ++s) {
            short8 bfr = *(const short8*)&cbuf[(Nt * 16 + n15) * CSTR + s * 32 + kg * 8];
            acc2[Nt] = __builtin_amdgcn_mfma_f32_16x16x32_bf16(w2[s], bfr, acc2[Nt], 0, 0, 0);
        }
    }
#pragma unroll
    for (int Nt = 0; Nt < 4; ++Nt) {
        int gy = y0 + Nt, gx = x0 + n15;
#pragma unroll
        for (int r = 0; r < 4; ++r) {
            int c = wv * 16 + hi4 + r;
            float v = fmaf(acc2[Nt][r], inv4[r], sh4[r]);
            out[((size_t)(b * 64 + c)) * 36864 + (size_t)gy * 192 + gx] = v > 0.f ? v : 0.f;
        }
    }
}

extern "C" void kernel_launch(void* const* d_in, const int* in_sizes, int n_in,
                              void* d_out, int out_size, void* d_ws, size_t ws_size,
                              hipStream_t stream) {
    float* out = (float*)d_out;   // reference output dtype is float32

    // ws: f1 | f2, each [4][192][192][64] bf16 (channel-last) = 18.87 MB
    unsigned short* f1 = (unsigned short*)d_ws;
    unsigned short* f2 = f1 + (size_t)4 * 64 * 36864;

    // Weight fragments in the TAIL of d_out (consumed by convs, then overwritten).
    unsigned short* wfK = (unsigned short*)d_out + 18800640;  // byte 37601280
    unsigned short* wfQ = wfK + 36864;                        // ends at 37748736

    prep_wfrag<<<dim3(2), 256, 0, stream>>>(
        (const float*)d_in[2], (const float*)d_in[8], wfK, wfQ);

    dim3 cgrid(12, 24, 8);    // z = which*4 + b : both convs in one dispatch
    conv3x3_mfma2<<<cgrid, 256, 0, stream>>>(
        (const float*)d_in[0], (const float*)d_in[1], wfK, wfQ,
        (const float*)d_in[3], (const float*)d_in[4], (const float*)d_in[5],
        (const float*)d_in[6], (const float*)d_in[7],
        (const float*)d_in[9], (const float*)d_in[10], (const float*)d_in[11],
        (const float*)d_in[12], (const float*)d_in[13],
        f1, f2);

    dim3 ggrid(12, 48, 4);
    corr_conv1x1_mfma<<<ggrid, 256, 0, stream>>>(
        f1, f2,
        (const float*)d_in[14], (const float*)d_in[15], (const float*)d_in[16],
        (const float*)d_in[17], (const float*)d_in[18], (const float*)d_in[19],
        out);
}

// Round 21
// 163.812 us; speedup vs baseline: 1.6276x; 1.6276x over previous
//
#include <hip/hip_runtime.h>

#define EPSf 1e-5f
#define NPAD 72     // f2w/win ci stride: 16B-aligned b128, 2-way-free banks
#define CSTR 168    // cbuf row stride: 336B, 16B-aligned, period-8 bank spread

typedef __attribute__((ext_vector_type(8))) short short8;
typedef __attribute__((ext_vector_type(4))) float f32x4;

static __device__ __forceinline__ unsigned short f32_to_bf16(float f) {
    unsigned int u = __float_as_uint(f);
    unsigned int r = (u + 0x7FFFu + ((u >> 16) & 1u)) >> 16;
    return (unsigned short)r;
}
static __device__ __forceinline__ float bf16_to_f32(unsigned short h) {
    return __uint_as_float(((unsigned int)h) << 16);
}

// Reorder conv weights into MFMA-fragment order (r17-validated). grid 2, block 256.
__global__ __launch_bounds__(256) void prep_wfrag(
    const float* __restrict__ wK, const float* __restrict__ wQ,
    unsigned short* __restrict__ fK, unsigned short* __restrict__ fQ)
{
    const float* src = (blockIdx.x == 0) ? wK : wQ;
    unsigned short* dst = (blockIdx.x == 0) ? fK : fQ;
    const int t = threadIdx.x;
#pragma unroll
    for (int it = 0; it < 18; ++it) {
        int s = t + it * 256;                 // 0..4607
        int l = s & 63, rest = s >> 6;
        int kc = rest % 18, wv = rest / 18;
        int n = l & 15, kg = l >> 4;
        int cout = wv * 16 + n, cih = kc & 1, tap = kc >> 1;
        short8 v;
#pragma unroll
        for (int e = 0; e < 8; ++e) {
            int ci = cih * 32 + kg * 8 + e;
            ((unsigned short*)&v)[e] = f32_to_bf16(src[(size_t)cout * 576 + ci * 9 + tap]);
        }
        *(short8*)&dst[(size_t)s * 8] = v;
    }
}

// Conv variant A — exact r19 structure (control; VGPR ~136, no min-waves bound).
__global__ __launch_bounds__(256) void conv3x3_mfma_A(
    const float* __restrict__ in,
    const unsigned short* __restrict__ wfrag,
    const float* __restrict__ bias,
    const float* __restrict__ bn_g, const float* __restrict__ bn_be,
    const float* __restrict__ bn_m, const float* __restrict__ bn_v,
    unsigned short* __restrict__ out)
{
    __shared__ unsigned short win[10 * 18 * NPAD];
    const int t  = threadIdx.x;
    const int x0 = blockIdx.x << 4, y0 = blockIdx.y << 3;
    const int b  = blockIdx.z;
    const float* inb = in + (size_t)b * 64 * 36864;

    if (x0 == 0) {
        for (int i = t; i < 640; i += 256) {
            int ci = i & 63, row = i >> 6;
            win[(row * 18 + 0) * NPAD + ci] = 0;
        }
    } else if (x0 == 176) {
        for (int i = t; i < 640; i += 256) {
            int ci = i & 63, row = i >> 6;
            win[(row * 18 + 17) * NPAD + ci] = 0;
        }
    }

    const int gxs = (x0 == 0) ? 0 : ((x0 == 176) ? 168 : x0 - 4);
#pragma unroll
    for (int it = 0; it < 15; ++it) {
        int q = t + (it << 8);
        int p = q / 6, j = q - p * 6;
        int ci = p & 63, row = p >> 6;
        int gy = y0 - 1 + row;
        bool rowok = (gy >= 0 && gy < 192);
        int gya = rowok ? gy : (gy < 0 ? 0 : 191);
        int gxa = gxs + j * 4;
        f32x4 v = *(const f32x4*)(inb + (size_t)ci * 36864 + gya * 192 + gxa);
#pragma unroll
        for (int e = 0; e < 4; ++e) {
            int col = gxa + e - (x0 - 1);
            if (col >= 0 && col < 18)
                win[(row * 18 + col) * NPAD + ci] = f32_to_bf16(rowok ? v[e] : 0.f);
        }
    }

    const int wv = t >> 6, l = t & 63;
    const int n  = l & 15, kg = l >> 4;
    const int cout = wv * 16 + n;
    short8 bfrag[18];
    const unsigned short* wf = wfrag + (size_t)wv * 9216 + l * 8;
#pragma unroll
    for (int kc = 0; kc < 18; ++kc)
        bfrag[kc] = *(const short8*)&wf[kc * 512];

    const float inv = bn_g[cout] / sqrtf(bn_v[cout] + EPSf);
    const float sh  = (bias[cout] - bn_m[cout]) * inv + bn_be[cout];

    f32x4 acc[8];
#pragma unroll
    for (int mt = 0; mt < 8; ++mt) acc[mt] = (f32x4){0.f, 0.f, 0.f, 0.f};

    __syncthreads();

#pragma unroll
    for (int kc = 0; kc < 18; ++kc) {
        int cih = kc & 1, tap = kc >> 1;
        int ky = tap / 3, kx = tap - ky * 3;
        const int cbase = cih * 32 + kg * 8;
        const int col = n + kx;
#pragma unroll
        for (int mt = 0; mt < 8; ++mt) {
            const unsigned short* ap = &win[((mt + ky) * 18 + col) * NPAD + cbase];
            short8 a = *(const short8*)ap;
            acc[mt] = __builtin_amdgcn_mfma_f32_16x16x32_bf16(a, bfrag[kc], acc[mt], 0, 0, 0);
        }
    }

    const size_t pbase = (size_t)b * 36864;
#pragma unroll
    for (int mt = 0; mt < 8; ++mt) {
#pragma unroll
        for (int r = 0; r < 4; ++r) {
            int pxx = kg * 4 + r;
            float v = fmaf(acc[mt][r], inv, sh);
            out[(pbase + (size_t)(y0 + mt) * 192 + x0 + pxx) * 64 + cout] =
                f32_to_bf16(v > 0.f ? v : 0.f);
        }
    }
}

// Conv variant B — ci-split 2-stage pipeline: stage ci[0,32) | barrier |
// {issue ci[32,64) staging, MFMA even-kc chunks (cih=0)} | barrier | odd-kc.
// Same math; staging latency of half 1 hides under half 0's 72 MFMAs.
__global__ __launch_bounds__(256) void conv3x3_mfma_B(
    const float* __restrict__ in,
    const unsigned short* __restrict__ wfrag,
    const float* __restrict__ bias,
    const float* __restrict__ bn_g, const float* __restrict__ bn_be,
    const float* __restrict__ bn_m, const float* __restrict__ bn_v,
    unsigned short* __restrict__ out)
{
    __shared__ unsigned short win[10 * 18 * NPAD];
    const int t  = threadIdx.x;
    const int x0 = blockIdx.x << 4, y0 = blockIdx.y << 3;
    const int b  = blockIdx.z;
    const float* inb = in + (size_t)b * 64 * 36864;

    if (x0 == 0) {
        for (int i = t; i < 640; i += 256) {
            int ci = i & 63, row = i >> 6;
            win[(row * 18 + 0) * NPAD + ci] = 0;
        }
    } else if (x0 == 176) {
        for (int i = t; i < 640; i += 256) {
            int ci = i & 63, row = i >> 6;
            win[(row * 18 + 17) * NPAD + ci] = 0;
        }
    }

    const int gxs = (x0 == 0) ? 0 : ((x0 == 176) ? 168 : x0 - 4);
    const int wv = t >> 6, l = t & 63;
    const int n  = l & 15, kg = l >> 4;
    const int cout = wv * 16 + n;

    short8 bfrag[18];
    const unsigned short* wf = wfrag + (size_t)wv * 9216 + l * 8;
#pragma unroll
    for (int kc = 0; kc < 18; ++kc)
        bfrag[kc] = *(const short8*)&wf[kc * 512];

    const float inv = bn_g[cout] / sqrtf(bn_v[cout] + EPSf);
    const float sh  = (bias[cout] - bn_m[cout]) * inv + bn_be[cout];

    f32x4 acc[8];
#pragma unroll
    for (int mt = 0; mt < 8; ++mt) acc[mt] = (f32x4){0.f, 0.f, 0.f, 0.f};

    // ---- stage half 0: ci[0,32), 1920 items ----
#pragma unroll
    for (int it = 0; it < 8; ++it) {
        int q = t + (it << 8);
        if (q < 1920) {
            int p = q / 6, j = q - p * 6;
            int ci = p & 31, row = p >> 5;
            int gy = y0 - 1 + row;
            bool rowok = (gy >= 0 && gy < 192);
            int gya = rowok ? gy : (gy < 0 ? 0 : 191);
            int gxa = gxs + j * 4;
            f32x4 v = *(const f32x4*)(inb + (size_t)ci * 36864 + gya * 192 + gxa);
#pragma unroll
            for (int e = 0; e < 4; ++e) {
                int col = gxa + e - (x0 - 1);
                if (col >= 0 && col < 18)
                    win[(row * 18 + col) * NPAD + ci] = f32_to_bf16(rowok ? v[e] : 0.f);
            }
        }
    }
    __syncthreads();

    // ---- issue half-1 staging (loads fly under the MFMAs below) ----
#pragma unroll
    for (int it = 0; it < 8; ++it) {
        int q = t + (it << 8);
        if (q < 1920) {
            int p = q / 6, j = q - p * 6;
            int ci = 32 + (p & 31), row = p >> 5;
            int gy = y0 - 1 + row;
            bool rowok = (gy >= 0 && gy < 192);
            int gya = rowok ? gy : (gy < 0 ? 0 : 191);
            int gxa = gxs + j * 4;
            f32x4 v = *(const f32x4*)(inb + (size_t)ci * 36864 + gya * 192 + gxa);
#pragma unroll
            for (int e = 0; e < 4; ++e) {
                int col = gxa + e - (x0 - 1);
                if (col >= 0 && col < 18)
                    win[(row * 18 + col) * NPAD + ci] = f32_to_bf16(rowok ? v[e] : 0.f);
            }
        }
    }

    // ---- MFMA on half 0: even kc (cih=0, ci[0,32)) ----
#pragma unroll
    for (int tap = 0; tap < 9; ++tap) {
        int kc = tap * 2;
        int ky = tap / 3, kx = tap - ky * 3;
        const int cbase = kg * 8;             // cih = 0
        const int col = n + kx;
#pragma unroll
        for (int mt = 0; mt < 8; ++mt) {
            const unsigned short* ap = &win[((mt + ky) * 18 + col) * NPAD + cbase];
            short8 a = *(const short8*)ap;
            acc[mt] = __builtin_amdgcn_mfma_f32_16x16x32_bf16(a, bfrag[kc], acc[mt], 0, 0, 0);
        }
    }
    __syncthreads();

    // ---- MFMA on half 1: odd kc (cih=1, ci[32,64)) ----
#pragma unroll
    for (int tap = 0; tap < 9; ++tap) {
        int kc = tap * 2 + 1;
        int ky = tap / 3, kx = tap - ky * 3;
        const int cbase = 32 + kg * 8;        // cih = 1
        const int col = n + kx;
#pragma unroll
        for (int mt = 0; mt < 8; ++mt) {
            const unsigned short* ap = &win[((mt + ky) * 18 + col) * NPAD + cbase];
            short8 a = *(const short8*)ap;
            acc[mt] = __builtin_amdgcn_mfma_f32_16x16x32_bf16(a, bfrag[kc], acc[mt], 0, 0, 0);
        }
    }

    const size_t pbase = (size_t)b * 36864;
#pragma unroll
    for (int mt = 0; mt < 8; ++mt) {
#pragma unroll
        for (int r = 0; r < 4; ++r) {
            int pxx = kg * 4 + r;
            float v = fmaf(acc[mt][r], inv, sh);
            out[(pbase + (size_t)(y0 + mt) * 192 + x0 + pxx) * 64 + cout] =
                f32_to_bf16(v > 0.f ? v : 0.f);
        }
    }
}

// Fused corr(R=4) + 1x1 conv, full MFMA — EXACT round-16 version (validated).
__global__ __launch_bounds__(256) void corr_conv1x1_mfma(
    const unsigned short* __restrict__ f1, const unsigned short* __restrict__ f2,
    const float* __restrict__ qw,
    const float* __restrict__ qb,
    const float* __restrict__ qg, const float* __restrict__ qbe,
    const float* __restrict__ qm, const float* __restrict__ qv,
    float* __restrict__ out)
{
    __shared__ unsigned short smem[20736 + 64 * CSTR];
    unsigned short* f2w  = smem;
    unsigned short* cbuf = smem + 20736;

    const int t  = threadIdx.x;
    const int x0 = blockIdx.x << 4, y0 = blockIdx.y << 2;
    const int b  = blockIdx.z;
    const int wv = t >> 6, l = t & 63;
    const int n15 = l & 15, kg = l >> 4, hi4 = kg << 2;
    const size_t pbase = (size_t)b * 36864;

#pragma unroll
    for (int i = 0; i < 9; ++i) {
        int q = t + (i << 8);
        int r = q / 192, rem = q - r * 192;
        int u = rem >> 3, j = rem & 7;
        int gy = y0 - 4 + r, gx = x0 - 4 + u;
        short8 v = {0, 0, 0, 0, 0, 0, 0, 0};
        if (gy >= 0 && gy < 192 && gx >= 0 && gx < 192)
            v = *(const short8*)&f2[(pbase + (size_t)gy * 192 + gx) * 64 + j * 8];
        *(short8*)&f2w[(r * 24 + u) * NPAD + j * 8] = v;
    }
#pragma unroll
    for (int i = 0; i < 2; ++i) {
        int q = t + (i << 8);
        int px = q >> 3, j = q & 7;
        int gy = y0 + (px >> 4), gx = x0 + (px & 15);
        short8 v = *(const short8*)&f1[(pbase + (size_t)gy * 192 + gx) * 64 + j * 8];
        *(short8*)&cbuf[px * CSTR + 88 + j * 8] = v;
    }
    if (t < 64) {
#pragma unroll
        for (int d = 81; d < 88; ++d)  cbuf[t * CSTR + d] = 0;
#pragma unroll
        for (int d = 152; d < 168; ++d) cbuf[t * CSTR + d] = 0;
    }

    const int cout_a = wv * 16 + n15;
    short8 w2[5];
#pragma unroll
    for (int s = 0; s < 5; ++s) {
        short8 v;
#pragma unroll
        for (int e = 0; e < 8; ++e) {
            int k = s * 32 + kg * 8 + e;
            float w = 0.f;
            if (k < 81)                  w = qw[cout_a * 145 + k];
            else if (k >= 88 && k < 152) w = qw[cout_a * 145 + k - 7];
            ((unsigned short*)&v)[e] = f32_to_bf16(w);
        }
        w2[s] = v;
    }
    float inv4[4], sh4[4];
#pragma unroll
    for (int r = 0; r < 4; ++r) {
        int c = wv * 16 + hi4 + r;
        inv4[r] = qg[c] / sqrtf(qv[c] + EPSf);
        sh4[r]  = (qb[c] - qm[c]) * inv4[r] + qbe[c];
    }

    __syncthreads();

    const int ty = wv, tx = n15;
    short8 bfr0 = *(const short8*)&cbuf[(ty * 16 + n15) * CSTR + 88 + kg * 8];
    short8 bfr1 = *(const short8*)&cbuf[(ty * 16 + n15) * CSTR + 120 + kg * 8];
    const int rowb = (ty * 16 + tx) * CSTR;
#pragma unroll
    for (int Mt = 0; Mt < 14; ++Mt) {
        int row = ty * 24 + Mt * 16 + n15;
        short8 a0 = *(const short8*)&f2w[row * NPAD + kg * 8];
        short8 a1 = *(const short8*)&f2w[row * NPAD + 32 + kg * 8];
        f32x4 acc = (f32x4){0.f, 0.f, 0.f, 0.f};
        acc = __builtin_amdgcn_mfma_f32_16x16x32_bf16(a0, bfr0, acc, 0, 0, 0);
        acc = __builtin_amdgcn_mfma_f32_16x16x32_bf16(a1, bfr1, acc, 0, 0, 0);
#pragma unroll
        for (int r = 0; r < 4; ++r) {
            int m  = Mt * 16 + hi4 + r;
            int bb = m / 24;
            int u  = m - bb * 24;
            int a  = u - tx;
            if (m < 216 && a >= 0 && a <= 8)
                cbuf[rowb + a * 9 + bb] = f32_to_bf16(acc[r] * 0.125f);
        }
    }
    __syncthreads();

    f32x4 acc2[4];
#pragma unroll
    for (int Nt = 0; Nt < 4; ++Nt) {
        acc2[Nt] = (f32x4){0.f, 0.f, 0.f, 0.f};
#pragma unroll
        for (int s = 0; s < 5; ++s) {
            short8 bfr = *(const short8*)&cbuf[(Nt * 16 + n15) * CSTR + s * 32 + kg * 8];
            acc2[Nt] = __builtin_amdgcn_mfma_f32_16x16x32_bf16(w2[s], bfr, acc2[Nt], 0, 0, 0);
        }
    }
#pragma unroll
    for (int Nt = 0; Nt < 4; ++Nt) {
        int gy = y0 + Nt, gx = x0 + n15;
#pragma unroll
        for (int r = 0; r < 4; ++r) {
            int c = wv * 16 + hi4 + r;
            float v = fmaf(acc2[Nt][r], inv4[r], sh4[r]);
            out[((size_t)(b * 64 + c)) * 36864 + (size_t)gy * 192 + gx] = v > 0.f ? v : 0.f;
        }
    }
}

extern "C" void kernel_launch(void* const* d_in, const int* in_sizes, int n_in,
                              void* d_out, int out_size, void* d_ws, size_t ws_size,
                              hipStream_t stream) {
    float* out = (float*)d_out;

    unsigned short* f1 = (unsigned short*)d_ws;
    unsigned short* f2 = f1 + (size_t)4 * 64 * 36864;

    unsigned short* wfK = (unsigned short*)d_out + 18800640;
    unsigned short* wfQ = wfK + 36864;

    prep_wfrag<<<dim3(2), 256, 0, stream>>>(
        (const float*)d_in[2], (const float*)d_in[8], wfK, wfQ);

    dim3 cgrid(12, 24, 4);
    // A/B experiment: fm1 via control structure, fm2 via ci-split pipeline.
    conv3x3_mfma_A<<<cgrid, 256, 0, stream>>>(
        (const float*)d_in[0], wfK, (const float*)d_in[3],
        (const float*)d_in[4], (const float*)d_in[5], (const float*)d_in[6],
        (const float*)d_in[7], f1);
    conv3x3_mfma_B<<<cgrid, 256, 0, stream>>>(
        (const float*)d_in[1], wfQ, (const float*)d_in[9],
        (const float*)d_in[10], (const float*)d_in[11], (const float*)d_in[12],
        (const float*)d_in[13], f2);

    dim3 ggrid(12, 48, 4);
    corr_conv1x1_mfma<<<ggrid, 256, 0, stream>>>(
        f1, f2,
        (const float*)d_in[14], (const float*)d_in[15], (const float*)d_in[16],
        (const float*)d_in[17], (const float*)d_in[18], (const float*)d_in[19],
        out);
}

// Round 22
// 138.622 us; speedup vs baseline: 1.9233x; 1.1817x over previous
//
#include <hip/hip_runtime.h>

#define EPSf 1e-5f
#define NPAD 72     // f2w/win ci stride: 16B-aligned b128, 2-way-free banks
#define CSTR 168    // cbuf row stride: 336B, 16B-aligned, period-8 bank spread

typedef __attribute__((ext_vector_type(8))) short short8;
typedef __attribute__((ext_vector_type(4))) float f32x4;

static __device__ __forceinline__ unsigned short f32_to_bf16(float f) {
    unsigned int u = __float_as_uint(f);
    unsigned int r = (u + 0x7FFFu + ((u >> 16) & 1u)) >> 16;
    return (unsigned short)r;
}
static __device__ __forceinline__ float bf16_to_f32(unsigned short h) {
    return __uint_as_float(((unsigned int)h) << 16);
}

// Reorder conv weights into MFMA-fragment order (r17-validated). grid 2, block 256.
__global__ __launch_bounds__(256) void prep_wfrag(
    const float* __restrict__ wK, const float* __restrict__ wQ,
    unsigned short* __restrict__ fK, unsigned short* __restrict__ fQ)
{
    const float* src = (blockIdx.x == 0) ? wK : wQ;
    unsigned short* dst = (blockIdx.x == 0) ? fK : fQ;
    const int t = threadIdx.x;
#pragma unroll
    for (int it = 0; it < 18; ++it) {
        int s = t + it * 256;                 // 0..4607
        int l = s & 63, rest = s >> 6;
        int kc = rest % 18, wv = rest / 18;
        int n = l & 15, kg = l >> 4;
        int cout = wv * 16 + n, cih = kc & 1, tap = kc >> 1;
        short8 v;
#pragma unroll
        for (int e = 0; e < 8; ++e) {
            int ci = cih * 32 + kg * 8 + e;
            ((unsigned short*)&v)[e] = f32_to_bf16(src[(size_t)cout * 576 + ci * 9 + tap]);
        }
        *(short8*)&dst[(size_t)s * 8] = v;
    }
}

// Both 3x3 convs, ONE dispatch, r21-validated ci-split 2-stage pipeline.
// grid (12,24,8): z = which*4 + b. NO min-waves bound (r20 spill lesson).
// Pipeline: stage ci[0,32) | barrier | {issue ci[32,64) staging, MFMA even-kc}
//           | barrier | MFMA odd-kc | BN+ReLU epilogue (channel-last bf16).
__global__ __launch_bounds__(256) void conv3x3_mfma_P(
    const float* __restrict__ fm1, const float* __restrict__ fm2,
    const unsigned short* __restrict__ wfK, const unsigned short* __restrict__ wfQ,
    const float* __restrict__ bK, const float* __restrict__ gK,
    const float* __restrict__ beK, const float* __restrict__ mK, const float* __restrict__ vK,
    const float* __restrict__ bQ, const float* __restrict__ gQ,
    const float* __restrict__ beQ, const float* __restrict__ mQ, const float* __restrict__ vQ,
    unsigned short* __restrict__ f1o, unsigned short* __restrict__ f2o)
{
    __shared__ unsigned short win[10 * 18 * NPAD];
    const int t  = threadIdx.x;
    const int x0 = blockIdx.x << 4, y0 = blockIdx.y << 3;
    const int b  = blockIdx.z & 3, which = blockIdx.z >> 2;
    const float* in = which ? fm2 : fm1;
    const unsigned short* wfrag = which ? wfQ : wfK;
    const float* bias = which ? bQ : bK;
    const float* bn_g = which ? gQ : gK;
    const float* bn_be = which ? beQ : beK;
    const float* bn_m = which ? mQ : mK;
    const float* bn_v = which ? vQ : vK;
    unsigned short* out = which ? f2o : f1o;
    const float* inb = in + (size_t)b * 64 * 36864;

    if (x0 == 0) {
        for (int i = t; i < 640; i += 256) {
            int ci = i & 63, row = i >> 6;
            win[(row * 18 + 0) * NPAD + ci] = 0;
        }
    } else if (x0 == 176) {
        for (int i = t; i < 640; i += 256) {
            int ci = i & 63, row = i >> 6;
            win[(row * 18 + 17) * NPAD + ci] = 0;
        }
    }

    const int gxs = (x0 == 0) ? 0 : ((x0 == 176) ? 168 : x0 - 4);
    const int wv = t >> 6, l = t & 63;
    const int n  = l & 15, kg = l >> 4;
    const int cout = wv * 16 + n;

    short8 bfrag[18];
    const unsigned short* wf = wfrag + (size_t)wv * 9216 + l * 8;
#pragma unroll
    for (int kc = 0; kc < 18; ++kc)
        bfrag[kc] = *(const short8*)&wf[kc * 512];

    const float inv = bn_g[cout] / sqrtf(bn_v[cout] + EPSf);
    const float sh  = (bias[cout] - bn_m[cout]) * inv + bn_be[cout];

    f32x4 acc[8];
#pragma unroll
    for (int mt = 0; mt < 8; ++mt) acc[mt] = (f32x4){0.f, 0.f, 0.f, 0.f};

    // ---- stage half 0: ci[0,32), 1920 items ----
#pragma unroll
    for (int it = 0; it < 8; ++it) {
        int q = t + (it << 8);
        if (q < 1920) {
            int p = q / 6, j = q - p * 6;
            int ci = p & 31, row = p >> 5;
            int gy = y0 - 1 + row;
            bool rowok = (gy >= 0 && gy < 192);
            int gya = rowok ? gy : (gy < 0 ? 0 : 191);
            int gxa = gxs + j * 4;
            f32x4 v = *(const f32x4*)(inb + (size_t)ci * 36864 + gya * 192 + gxa);
#pragma unroll
            for (int e = 0; e < 4; ++e) {
                int col = gxa + e - (x0 - 1);
                if (col >= 0 && col < 18)
                    win[(row * 18 + col) * NPAD + ci] = f32_to_bf16(rowok ? v[e] : 0.f);
            }
        }
    }
    __syncthreads();

    // ---- issue half-1 staging (loads fly under the even-kc MFMAs) ----
#pragma unroll
    for (int it = 0; it < 8; ++it) {
        int q = t + (it << 8);
        if (q < 1920) {
            int p = q / 6, j = q - p * 6;
            int ci = 32 + (p & 31), row = p >> 5;
            int gy = y0 - 1 + row;
            bool rowok = (gy >= 0 && gy < 192);
            int gya = rowok ? gy : (gy < 0 ? 0 : 191);
            int gxa = gxs + j * 4;
            f32x4 v = *(const f32x4*)(inb + (size_t)ci * 36864 + gya * 192 + gxa);
#pragma unroll
            for (int e = 0; e < 4; ++e) {
                int col = gxa + e - (x0 - 1);
                if (col >= 0 && col < 18)
                    win[(row * 18 + col) * NPAD + ci] = f32_to_bf16(rowok ? v[e] : 0.f);
            }
        }
    }

    // ---- MFMA on half 0: even kc (cih=0, ci[0,32)) ----
#pragma unroll
    for (int tap = 0; tap < 9; ++tap) {
        int kc = tap * 2;
        int ky = tap / 3, kx = tap - ky * 3;
        const int cbase = kg * 8;
        const int col = n + kx;
#pragma unroll
        for (int mt = 0; mt < 8; ++mt) {
            const unsigned short* ap = &win[((mt + ky) * 18 + col) * NPAD + cbase];
            short8 a = *(const short8*)ap;
            acc[mt] = __builtin_amdgcn_mfma_f32_16x16x32_bf16(a, bfrag[kc], acc[mt], 0, 0, 0);
        }
    }
    __syncthreads();

    // ---- MFMA on half 1: odd kc (cih=1, ci[32,64)) ----
#pragma unroll
    for (int tap = 0; tap < 9; ++tap) {
        int kc = tap * 2 + 1;
        int ky = tap / 3, kx = tap - ky * 3;
        const int cbase = 32 + kg * 8;
        const int col = n + kx;
#pragma unroll
        for (int mt = 0; mt < 8; ++mt) {
            const unsigned short* ap = &win[((mt + ky) * 18 + col) * NPAD + cbase];
            short8 a = *(const short8*)ap;
            acc[mt] = __builtin_amdgcn_mfma_f32_16x16x32_bf16(a, bfrag[kc], acc[mt], 0, 0, 0);
        }
    }

    const size_t pbase = (size_t)b * 36864;
#pragma unroll
    for (int mt = 0; mt < 8; ++mt) {
#pragma unroll
        for (int r = 0; r < 4; ++r) {
            int pxx = kg * 4 + r;
            float v = fmaf(acc[mt][r], inv, sh);
            out[(pbase + (size_t)(y0 + mt) * 192 + x0 + pxx) * 64 + cout] =
                f32_to_bf16(v > 0.f ? v : 0.f);
        }
    }
}

// Fused corr(R=4) + 1x1 conv, full MFMA — EXACT round-16 version (validated).
__global__ __launch_bounds__(256) void corr_conv1x1_mfma(
    const unsigned short* __restrict__ f1, const unsigned short* __restrict__ f2,
    const float* __restrict__ qw,
    const float* __restrict__ qb,
    const float* __restrict__ qg, const float* __restrict__ qbe,
    const float* __restrict__ qm, const float* __restrict__ qv,
    float* __restrict__ out)
{
    __shared__ unsigned short smem[20736 + 64 * CSTR];
    unsigned short* f2w  = smem;
    unsigned short* cbuf = smem + 20736;

    const int t  = threadIdx.x;
    const int x0 = blockIdx.x << 4, y0 = blockIdx.y << 2;
    const int b  = blockIdx.z;
    const int wv = t >> 6, l = t & 63;
    const int n15 = l & 15, kg = l >> 4, hi4 = kg << 2;
    const size_t pbase = (size_t)b * 36864;

#pragma unroll
    for (int i = 0; i < 9; ++i) {
        int q = t + (i << 8);
        int r = q / 192, rem = q - r * 192;
        int u = rem >> 3, j = rem & 7;
        int gy = y0 - 4 + r, gx = x0 - 4 + u;
        short8 v = {0, 0, 0, 0, 0, 0, 0, 0};
        if (gy >= 0 && gy < 192 && gx >= 0 && gx < 192)
            v = *(const short8*)&f2[(pbase + (size_t)gy * 192 + gx) * 64 + j * 8];
        *(short8*)&f2w[(r * 24 + u) * NPAD + j * 8] = v;
    }
#pragma unroll
    for (int i = 0; i < 2; ++i) {
        int q = t + (i << 8);
        int px = q >> 3, j = q & 7;
        int gy = y0 + (px >> 4), gx = x0 + (px & 15);
        short8 v = *(const short8*)&f1[(pbase + (size_t)gy * 192 + gx) * 64 + j * 8];
        *(short8*)&cbuf[px * CSTR + 88 + j * 8] = v;
    }
    if (t < 64) {
#pragma unroll
        for (int d = 81; d < 88; ++d)  cbuf[t * CSTR + d] = 0;
#pragma unroll
        for (int d = 152; d < 168; ++d) cbuf[t * CSTR + d] = 0;
    }

    const int cout_a = wv * 16 + n15;
    short8 w2[5];
#pragma unroll
    for (int s = 0; s < 5; ++s) {
        short8 v;
#pragma unroll
        for (int e = 0; e < 8; ++e) {
            int k = s * 32 + kg * 8 + e;
            float w = 0.f;
            if (k < 81)                  w = qw[cout_a * 145 + k];
            else if (k >= 88 && k < 152) w = qw[cout_a * 145 + k - 7];
            ((unsigned short*)&v)[e] = f32_to_bf16(w);
        }
        w2[s] = v;
    }
    float inv4[4], sh4[4];
#pragma unroll
    for (int r = 0; r < 4; ++r) {
        int c = wv * 16 + hi4 + r;
        inv4[r] = qg[c] / sqrtf(qv[c] + EPSf);
        sh4[r]  = (qb[c] - qm[c]) * inv4[r] + qbe[c];
    }

    __syncthreads();

    const int ty = wv, tx = n15;
    short8 bfr0 = *(const short8*)&cbuf[(ty * 16 + n15) * CSTR + 88 + kg * 8];
    short8 bfr1 = *(const short8*)&cbuf[(ty * 16 + n15) * CSTR + 120 + kg * 8];
    const int rowb = (ty * 16 + tx) * CSTR;
#pragma unroll
    for (int Mt = 0; Mt < 14; ++Mt) {
        int row = ty * 24 + Mt * 16 + n15;
        short8 a0 = *(const short8*)&f2w[row * NPAD + kg * 8];
        short8 a1 = *(const short8*)&f2w[row * NPAD + 32 + kg * 8];
        f32x4 acc = (f32x4){0.f, 0.f, 0.f, 0.f};
        acc = __builtin_amdgcn_mfma_f32_16x16x32_bf16(a0, bfr0, acc, 0, 0, 0);
        acc = __builtin_amdgcn_mfma_f32_16x16x32_bf16(a1, bfr1, acc, 0, 0, 0);
#pragma unroll
        for (int r = 0; r < 4; ++r) {
            int m  = Mt * 16 + hi4 + r;
            int bb = m / 24;
            int u  = m - bb * 24;
            int a  = u - tx;
            if (m < 216 && a >= 0 && a <= 8)
                cbuf[rowb + a * 9 + bb] = f32_to_bf16(acc[r] * 0.125f);
        }
    }
    __syncthreads();

    f32x4 acc2[4];
#pragma unroll
    for (int Nt = 0; Nt < 4; ++Nt) {
        acc2[Nt] = (f32x4){0.f, 0.f, 0.f, 0.f};
#pragma unroll
        for (int s = 0; s < 5; ++s) {
            short8 bfr = *(const short8*)&cbuf[(Nt * 16 + n15) * CSTR + s * 32 + kg * 8];
            acc2[Nt] = __builtin_amdgcn_mfma_f32_16x16x32_bf16(w2[s], bfr, acc2[Nt], 0, 0, 0);
        }
    }
#pragma unroll
    for (int Nt = 0; Nt < 4; ++Nt) {
        int gy = y0 + Nt, gx = x0 + n15;
#pragma unroll
        for (int r = 0; r < 4; ++r) {
            int c = wv * 16 + hi4 + r;
            float v = fmaf(acc2[Nt][r], inv4[r], sh4[r]);
            out[((size_t)(b * 64 + c)) * 36864 + (size_t)gy * 192 + gx] = v > 0.f ? v : 0.f;
        }
    }
}

extern "C" void kernel_launch(void* const* d_in, const int* in_sizes, int n_in,
                              void* d_out, int out_size, void* d_ws, size_t ws_size,
                              hipStream_t stream) {
    float* out = (float*)d_out;

    unsigned short* f1 = (unsigned short*)d_ws;
    unsigned short* f2 = f1 + (size_t)4 * 64 * 36864;

    unsigned short* wfK = (unsigned short*)d_out + 18800640;
    unsigned short* wfQ = wfK + 36864;

    prep_wfrag<<<dim3(2), 256, 0, stream>>>(
        (const float*)d_in[2], (const float*)d_in[8], wfK, wfQ);

    dim3 cgrid(12, 24, 8);    // both convs in one dispatch: z = which*4 + b
    conv3x3_mfma_P<<<cgrid, 256, 0, stream>>>(
        (const float*)d_in[0], (const float*)d_in[1], wfK, wfQ,
        (const float*)d_in[3], (const float*)d_in[4], (const float*)d_in[5],
        (const float*)d_in[6], (const float*)d_in[7],
        (const float*)d_in[9], (const float*)d_in[10], (const float*)d_in[11],
        (const float*)d_in[12], (const float*)d_in[13],
        f1, f2);

    dim3 ggrid(12, 48, 4);
    corr_conv1x1_mfma<<<ggrid, 256, 0, stream>>>(
        f1, f2,
        (const float*)d_in[14], (const float*)d_in[15], (const float*)d_in[16],
        (const float*)d_in[17], (const float*)d_in[18], (const float*)d_in[19],
        out);
}